// Round 7
// baseline (750.184 us; speedup 1.0000x reference)
//
#include <hip/hip_runtime.h>
#include <hip/hip_bf16.h>

#define N_LITS    131072
#define N_CLAUSES 65536
#define N_EDGES   524288
#define FEAT      384
#define F2        768
#define H1        256
#define H2        64

#define NBUCKET   8192   // j >> 3

typedef __bf16 bf16_t;
typedef __attribute__((ext_vector_type(8))) __bf16 bf16x8;
typedef __attribute__((ext_vector_type(4))) __bf16 bf16x4;
typedef __attribute__((ext_vector_type(4))) float f32x4;

// ---- workspace layout (bytes) ----
#define OFF_W1T   0                               // bf16 [256][768]
#define OFF_W2T   (OFF_W1T + 256 * 768 * 2)       // bf16 [64][256]
#define OFF_W3T   (OFF_W2T + 64 * 256 * 2)        // bf16 [32][64]
#define OFF_SC    (OFF_W3T + 32 * 64 * 2)         // f32 [65536][2] {sum,count}
#define OFF_HIST  (OFF_SC + 65536 * 8)            // int [8192]
#define OFF_CURS  (OFF_HIST + NBUCKET * 4)        // int [8192]
#define OFF_PAIRS (OFF_CURS + NBUCKET * 4)        // int2 [524288] (i,j) bucketed
#define OFF_X     (OFF_PAIRS + (size_t)N_EDGES * 8)
#define XL_BYTES  ((size_t)N_LITS * H1 * 2)
#define XC_BYTES  ((size_t)N_CLAUSES * H1 * 2)

// LDS strides (elements)
#define XSTR  264  // k_pre epilogue row stride: 256 + 8 pad
#define H2STR 72   // h2 row stride: 64 + 8 pad

// Fused: transpose+cast W1,W2,W3; zero sc; zero hist.
// weights [0,215040); sc zero [215040,247808) as float4; hist zero [247808,249856) as int4.
__global__ void k_prep(const float* __restrict__ W1, const float* __restrict__ W2,
                       const float* __restrict__ W3, bf16_t* __restrict__ W1T,
                       bf16_t* __restrict__ W2T, bf16_t* __restrict__ W3T,
                       float4* __restrict__ scz, int4* __restrict__ histz) {
  int idx = blockIdx.x * blockDim.x + threadIdx.x;
  if (idx < 196608) {
    int n = idx / 768, k = idx - n * 768;
    W1T[idx] = (bf16_t)W1[k * 256 + n];
  } else if (idx < 196608 + 16384) {
    int i = idx - 196608;
    int n = i / 256, k = i - n * 256;
    W2T[i] = (bf16_t)W2[k * 64 + n];
  } else if (idx < 196608 + 16384 + 2048) {
    int i = idx - 196608 - 16384;
    int n = i / 64, k = i - n * 64;
    W3T[i] = (bf16_t)((n < 20) ? W3[k * 20 + n] : 0.0f);
  } else if (idx >= 215040 && idx < 247808) {
    scz[idx - 215040] = (float4){0.f, 0.f, 0.f, 0.f};
  } else if (idx >= 247808 && idx < 249856) {
    histz[idx - 247808] = (int4){0, 0, 0, 0};
  }
}

// ---- edge bucketing: hist -> scan -> scatter (order-invariant permutation) ----
__global__ void k_bin_count(const int* __restrict__ edge_j, int* __restrict__ hist) {
  int e = blockIdx.x * blockDim.x + threadIdx.x;
  if (e < N_EDGES) atomicAdd(&hist[edge_j[e] >> 3], 1);
}

// single block, 256 threads: exclusive scan of hist[8192] -> cursor[8192]
__global__ void k_scan(const int* __restrict__ hist, int* __restrict__ cursor) {
  __shared__ int partial[256];
  int t = threadIdx.x;
  int base = t * 32;
  int local[32];
  int s = 0;
#pragma unroll
  for (int k = 0; k < 32; ++k) { local[k] = s; s += hist[base + k]; }
  partial[t] = s;
  __syncthreads();
  if (t == 0) {
    int acc = 0;
    for (int k = 0; k < 256; ++k) { int v = partial[k]; partial[k] = acc; acc += v; }
  }
  __syncthreads();
  int off = partial[t];
#pragma unroll
  for (int k = 0; k < 32; ++k) cursor[base + k] = off + local[k];
}

__global__ void k_scatter(const int* __restrict__ edge_i, const int* __restrict__ edge_j,
                          int* __restrict__ cursor, int2* __restrict__ pairs) {
  int e = blockIdx.x * blockDim.x + threadIdx.x;
  if (e >= N_EDGES) return;
  int j = edge_j[e];
  int pos = atomicAdd(&cursor[j >> 3], 1);
  pairs[pos] = (int2){edge_i[e], j};
}

// ---- precompute: XL = l_embs @ W1_top ; XC = c_embs @ W1_bot + b1 (bf16 out) ----
// Barrier-free main loop: each wave loads its A-fragments directly from global f32
// (4x intra-block redundancy absorbed by L2); LDS used only for the store transpose.
__global__ __launch_bounds__(256, 3) void k_pre(
    const float* __restrict__ l_embs, const float* __restrict__ c_embs,
    const bf16_t* __restrict__ W1T, const float* __restrict__ b1,
    bf16_t* __restrict__ XLb, bf16_t* __restrict__ XCb)
{
  __shared__ __align__(16) bf16_t smem2[64 * XSTR];  // epilogue transpose only

  const int t    = threadIdx.x;
  const int wave = t >> 6;
  const int lane = t & 63;
  const int m    = lane & 15;
  const int quad = lane >> 4;
  const int bid  = blockIdx.x;
  const bool isC = bid >= (N_LITS / 64);
  const int r0   = (isC ? bid - N_LITS / 64 : bid) * 64;
  const float* A = isC ? c_embs : l_embs;
  const int koff = isC ? FEAT : 0;
  const int wn   = wave * 64;

  f32x4 acc[4][4];
#pragma unroll
  for (int mt = 0; mt < 4; ++mt)
#pragma unroll
    for (int nt = 0; nt < 4; ++nt) acc[mt][nt] = (f32x4){0.f, 0.f, 0.f, 0.f};

  const float*  pa0 = A + (size_t)(r0 + m) * FEAT + quad * 8;
  const bf16_t* wb1 = W1T + (size_t)(wn + m) * F2 + koff + quad * 8;

#pragma unroll 2
  for (int s = 0; s < 12; ++s) {   // K=384 in steps of 32
    bf16x8 af[4];
#pragma unroll
    for (int mt = 0; mt < 4; ++mt) {
      const float* pa = pa0 + (size_t)mt * 16 * FEAT + s * 32;
      float4 u0 = *(const float4*)(pa);
      float4 u1 = *(const float4*)(pa + 4);
      af[mt][0] = (bf16_t)u0.x; af[mt][1] = (bf16_t)u0.y;
      af[mt][2] = (bf16_t)u0.z; af[mt][3] = (bf16_t)u0.w;
      af[mt][4] = (bf16_t)u1.x; af[mt][5] = (bf16_t)u1.y;
      af[mt][6] = (bf16_t)u1.z; af[mt][7] = (bf16_t)u1.w;
    }
#pragma unroll
    for (int nt = 0; nt < 4; ++nt) {
      bf16x8 b = *(const bf16x8*)(wb1 + (size_t)nt * 16 * F2 + s * 32);
#pragma unroll
      for (int mt = 0; mt < 4; ++mt)
        acc[mt][nt] = __builtin_amdgcn_mfma_f32_16x16x32_bf16(af[mt], b, acc[mt][nt], 0, 0, 0);
    }
  }

  // ---- epilogue: fragments -> LDS transpose -> coalesced bf16x8 stores ----
#pragma unroll
  for (int nt = 0; nt < 4; ++nt) {
    int col = wn + nt * 16 + m;
    float badd = isC ? b1[col] : 0.0f;
#pragma unroll
    for (int mt = 0; mt < 4; ++mt)
#pragma unroll
      for (int r = 0; r < 4; ++r)
        smem2[(mt * 16 + quad * 4 + r) * XSTR + col] = (bf16_t)(acc[mt][nt][r] + badd);
  }
  __syncthreads();

  bf16_t* X = isC ? XCb : XLb;
#pragma unroll
  for (int k = 0; k < 8; ++k) {
    int c    = t + k * 256;
    int row  = c >> 5;           // 32 chunks per row -> row in [0,64)
    int coff = (c & 31) * 8;
    bf16x8 v = *(const bf16x8*)(smem2 + row * XSTR + coff);
    *(bf16x8*)(X + (size_t)(r0 + row) * H1 + coff) = v;
  }
}

// ---- per-edge: h1 = relu(XL[i] + XC[j]) in-register, layers 2-4, atomics ----
// Processes the j-bucketed pairs list; XCD-chunked swizzle -> each XCD's L2 holds
// its contiguous j-range of XC. 64 edges/block, 4 waves x 16 edges, no barriers.
__global__ __launch_bounds__(256, 8) void k_edge2(
    const bf16_t* __restrict__ XLb, const bf16_t* __restrict__ XCb,
    const int2* __restrict__ pairs,
    const bf16_t* __restrict__ W2T, const bf16_t* __restrict__ W3T,
    const float* __restrict__ b2, const float* __restrict__ b3,
    const float* __restrict__ W4, const float* __restrict__ b4,
    float* __restrict__ sc)
{
  __shared__ __align__(16) bf16_t h2s[64 * H2STR];

  const int t    = threadIdx.x;
  const int wave = t >> 6;
  const int lane = t & 63;
  const int m    = lane & 15;
  const int quad = lane >> 4;
  // bijective XCD-chunked swizzle (grid 8192 % 8 == 0)
  const int bid  = blockIdx.x;
  const int swz  = (bid & 7) * (int)(gridDim.x >> 3) + (bid >> 3);
  const int e0   = swz * 64;
  const int er   = wave * 16;

  const int2 ij = pairs[e0 + er + m];
  const int ri = ij.x;
  const int rj = ij.y;
  const size_t baseL = (size_t)ri * H1;
  const size_t baseC = (size_t)rj * H1;

  f32x4 acc2[4];
#pragma unroll
  for (int nt = 0; nt < 4; ++nt) acc2[nt] = (f32x4){0.f, 0.f, 0.f, 0.f};

  // layer 2: K=256 in 8 steps of 32; A built in-register from gathered rows
#pragma unroll
  for (int g = 0; g < 2; ++g) {
    bf16x8 xa[4], ya[4];
#pragma unroll
    for (int u = 0; u < 4; ++u) {
      const int off = (g * 4 + u) * 32 + quad * 8;
      xa[u] = *(const bf16x8*)(XLb + baseL + off);
      ya[u] = *(const bf16x8*)(XCb + baseC + off);
    }
    bf16x8 a2[4];
#pragma unroll
    for (int u = 0; u < 4; ++u) {
#pragma unroll
      for (int jj = 0; jj < 8; ++jj)
        a2[u][jj] = (bf16_t)fmaxf((float)xa[u][jj] + (float)ya[u][jj], 0.f);
    }
#pragma unroll
    for (int u = 0; u < 4; ++u) {
      const int s2 = g * 4 + u;
#pragma unroll
      for (int nt = 0; nt < 4; ++nt) {
        bf16x8 b = *(const bf16x8*)(W2T + (size_t)(nt * 16 + m) * H1 + s2 * 32 + quad * 8);
        acc2[nt] = __builtin_amdgcn_mfma_f32_16x16x32_bf16(a2[u], b, acc2[nt], 0, 0, 0);
      }
    }
  }

  // h2 -> LDS (rows er..er+15 owned by this wave; no barrier needed)
#pragma unroll
  for (int nt = 0; nt < 4; ++nt) {
    float bb = b2[nt * 16 + m];
#pragma unroll
    for (int r = 0; r < 4; ++r)
      h2s[(er + quad * 4 + r) * H2STR + nt * 16 + m] =
          (bf16_t)fmaxf(acc2[nt][r] + bb, 0.0f);
  }

  // layer 3: C3[16,32] = h2[16,64] @ W3pad
  f32x4 acc3[2];
#pragma unroll
  for (int nt = 0; nt < 2; ++nt) acc3[nt] = (f32x4){0.f, 0.f, 0.f, 0.f};
#pragma unroll
  for (int s3 = 0; s3 < 2; ++s3) {
    bf16x8 a3 = *(const bf16x8*)(h2s + (er + m) * H2STR + s3 * 32 + quad * 8);
#pragma unroll
    for (int nt = 0; nt < 2; ++nt) {
      bf16x8 b = *(const bf16x8*)(W3T + (size_t)(nt * 16 + m) * H2 + s3 * 32 + quad * 8);
      acc3[nt] = __builtin_amdgcn_mfma_f32_16x16x32_bf16(a3, b, acc3[nt], 0, 0, 0);
    }
  }

  // layer 4 + per-clause atomics (interleaved {sum,count})
  float b3A = b3[m];
  float b3B = (m + 16 < 20) ? b3[m + 16] : 0.0f;
  float w4A = W4[m];
  float w4B = (m + 16 < 20) ? W4[m + 16] : 0.0f;

  float p[4];
#pragma unroll
  for (int r = 0; r < 4; ++r) {
    float hA = fmaxf(acc3[0][r] + b3A, 0.0f);
    float hB = fmaxf(acc3[1][r] + b3B, 0.0f);
    p[r] = hA * w4A + hB * w4B;
  }
#pragma unroll
  for (int d = 1; d < 16; d <<= 1) {
#pragma unroll
    for (int r = 0; r < 4; ++r) p[r] += __shfl_xor(p[r], d, 64);
  }

  // shfl must run with ALL lanes active (inactive-source shfl is undefined):
  // row er+quad*4+r's j lives in lane quad*4+r (that lane's m == quad*4+r).
  int ejr[4];
#pragma unroll
  for (int r = 0; r < 4; ++r) ejr[r] = __shfl(rj, quad * 4 + r, 64);

  if (m == 0) {
    float bb4 = b4[0];
#pragma unroll
    for (int r = 0; r < 4; ++r) {
      atomicAdd(&sc[2 * ejr[r]], p[r] + bb4);
      atomicAdd(&sc[2 * ejr[r] + 1], 1.0f);
    }
  }
}

// out[e] = sc[ej].sum / max(sc[ej].count, 1) — one 8B gather per edge
__global__ void k_gather(const float2* __restrict__ sc,
                         const int* __restrict__ edge_j, float* __restrict__ out) {
  int e = blockIdx.x * blockDim.x + threadIdx.x;
  if (e >= N_EDGES) return;
  float2 v = sc[edge_j[e]];
  out[e] = v.x / fmaxf(v.y, 1.0f);
}

extern "C" void kernel_launch(void* const* d_in, const int* in_sizes, int n_in,
                              void* d_out, int out_size, void* d_ws, size_t ws_size,
                              hipStream_t stream) {
  const float* l_embs = (const float*)d_in[0];
  const float* c_embs = (const float*)d_in[1];
  const int*   edge_i = (const int*)d_in[2];
  const int*   edge_j = (const int*)d_in[3];
  const float* W1 = (const float*)d_in[4];
  const float* b1 = (const float*)d_in[5];
  const float* W2 = (const float*)d_in[6];
  const float* b2 = (const float*)d_in[7];
  const float* W3 = (const float*)d_in[8];
  const float* b3 = (const float*)d_in[9];
  const float* W4 = (const float*)d_in[10];
  const float* b4 = (const float*)d_in[11];
  float* out = (float*)d_out;

  char* ws = (char*)d_ws;
  bf16_t* W1T  = (bf16_t*)(ws + OFF_W1T);
  bf16_t* W2T  = (bf16_t*)(ws + OFF_W2T);
  bf16_t* W3T  = (bf16_t*)(ws + OFF_W3T);
  float*  sc   = (float*)(ws + OFF_SC);
  int*    hist = (int*)(ws + OFF_HIST);
  int*    curs = (int*)(ws + OFF_CURS);
  int2*   pairs= (int2*)(ws + OFF_PAIRS);
  bf16_t* XLb  = (bf16_t*)(ws + OFF_X);
  bf16_t* XCb  = (bf16_t*)(ws + OFF_X + XL_BYTES);

  // weights transpose + sc/hist zeroing (976 blocks x 256 = 249856 threads)
  k_prep<<<976, 256, 0, stream>>>(W1, W2, W3, W1T, W2T, W3T,
                                  (float4*)sc, (int4*)hist);

  // j-bucketing of edges (order-invariant)
  k_bin_count<<<N_EDGES / 256, 256, 0, stream>>>(edge_j, hist);
  k_scan<<<1, 256, 0, stream>>>(hist, curs);
  k_scatter<<<N_EDGES / 256, 256, 0, stream>>>(edge_i, edge_j, curs, pairs);

  const int pre_grid = N_LITS / 64 + N_CLAUSES / 64;  // 3072
  k_pre<<<pre_grid, 256, 0, stream>>>(l_embs, c_embs, W1T, b1, XLb, XCb);

  k_edge2<<<N_EDGES / 64, 256, 0, stream>>>(
      XLb, XCb, pairs, W2T, W3T, b2, b3, W4, b4, sc);

  k_gather<<<N_EDGES / 256, 256, 0, stream>>>((const float2*)sc, edge_j, out);
}

// Round 8
// 677.193 us; speedup vs baseline: 1.1078x; 1.1078x over previous
//
#include <hip/hip_runtime.h>
#include <hip/hip_bf16.h>

#define N_LITS    131072
#define N_CLAUSES 65536
#define N_EDGES   524288
#define FEAT      384
#define F2        768
#define H1        256
#define H2        64

#define NBUCKET   8192   // j >> 3

typedef __bf16 bf16_t;
typedef __attribute__((ext_vector_type(8))) __bf16 bf16x8;
typedef __attribute__((ext_vector_type(4))) __bf16 bf16x4;
typedef __attribute__((ext_vector_type(4))) float f32x4;

// ---- workspace layout (bytes) ----
#define OFF_W1T   0                               // bf16 [256][768]
#define OFF_W2T   (OFF_W1T + 256 * 768 * 2)       // bf16 [64][256]
#define OFF_W3T   (OFF_W2T + 64 * 256 * 2)        // bf16 [32][64]
#define OFF_SC    (OFF_W3T + 32 * 64 * 2)         // f32 [65536][2] {sum,count}
#define OFF_HIST  (OFF_SC + 65536 * 8)            // int [8192]
#define OFF_CURS  (OFF_HIST + NBUCKET * 4)        // int [8192]
#define OFF_PAIRS (OFF_CURS + NBUCKET * 4)        // int2 [524288] (i,j) bucketed
#define OFF_X     (OFF_PAIRS + (size_t)N_EDGES * 8)
#define XL_BYTES  ((size_t)N_LITS * H1 * 2)
#define XC_BYTES  ((size_t)N_CLAUSES * H1 * 2)

// LDS strides (elements)
#define ASTR  104  // Abuf staging row stride: 96 + 8 pad
#define XSTR  264  // k_pre epilogue row stride: 256 + 8 pad
#define H2STR 72   // h2 row stride: 64 + 8 pad

// Fused: transpose+cast W1,W2,W3; zero sc; zero hist.
__global__ void k_prep(const float* __restrict__ W1, const float* __restrict__ W2,
                       const float* __restrict__ W3, bf16_t* __restrict__ W1T,
                       bf16_t* __restrict__ W2T, bf16_t* __restrict__ W3T,
                       float4* __restrict__ scz, int4* __restrict__ histz) {
  int idx = blockIdx.x * blockDim.x + threadIdx.x;
  if (idx < 196608) {
    int n = idx / 768, k = idx - n * 768;
    W1T[idx] = (bf16_t)W1[k * 256 + n];
  } else if (idx < 196608 + 16384) {
    int i = idx - 196608;
    int n = i / 256, k = i - n * 256;
    W2T[i] = (bf16_t)W2[k * 64 + n];
  } else if (idx < 196608 + 16384 + 2048) {
    int i = idx - 196608 - 16384;
    int n = i / 64, k = i - n * 64;
    W3T[i] = (bf16_t)((n < 20) ? W3[k * 20 + n] : 0.0f);
  } else if (idx >= 215040 && idx < 247808) {
    scz[idx - 215040] = (float4){0.f, 0.f, 0.f, 0.f};
  } else if (idx >= 247808 && idx < 249856) {
    histz[idx - 247808] = (int4){0, 0, 0, 0};
  }
}

// ---- edge bucketing: hist -> scan -> scatter (order-invariant permutation) ----
__global__ void k_bin_count(const int* __restrict__ edge_j, int* __restrict__ hist) {
  int e = blockIdx.x * blockDim.x + threadIdx.x;
  if (e < N_EDGES) atomicAdd(&hist[edge_j[e] >> 3], 1);
}

// single block, 256 threads: exclusive scan of hist[8192] -> cursor[8192]
__global__ void k_scan(const int* __restrict__ hist, int* __restrict__ cursor) {
  __shared__ int partial[256];
  int t = threadIdx.x;
  int base = t * 32;
  int local[32];
  int s = 0;
#pragma unroll
  for (int k = 0; k < 32; ++k) { local[k] = s; s += hist[base + k]; }
  partial[t] = s;
  __syncthreads();
  if (t == 0) {
    int acc = 0;
    for (int k = 0; k < 256; ++k) { int v = partial[k]; partial[k] = acc; acc += v; }
  }
  __syncthreads();
  int off = partial[t];
#pragma unroll
  for (int k = 0; k < 32; ++k) cursor[base + k] = off + local[k];
}

__global__ void k_scatter(const int* __restrict__ edge_i, const int* __restrict__ edge_j,
                          int* __restrict__ cursor, int2* __restrict__ pairs) {
  int e = blockIdx.x * blockDim.x + threadIdx.x;
  if (e >= N_EDGES) return;
  int j = edge_j[e];
  int pos = atomicAdd(&cursor[j >> 3], 1);
  pairs[pos] = (int2){edge_i[e], j};
}

// ---- precompute: XL = l_embs @ W1_top ; XC = c_embs @ W1_bot + b1 (bf16 out) ----
// Staged (round-5 form, known-good): cooperative coalesced LDS staging with
// register prefetch of the next chunk; occupancy bumped 3 -> 4 blocks/CU.
__global__ __launch_bounds__(256, 4) void k_pre(
    const float* __restrict__ l_embs, const float* __restrict__ c_embs,
    const bf16_t* __restrict__ W1T, const float* __restrict__ b1,
    bf16_t* __restrict__ XLb, bf16_t* __restrict__ XCb)
{
  __shared__ __align__(16) bf16_t smem2[64 * XSTR];  // staging (ASTR view) U epilogue
  bf16_t* Abuf = smem2;

  const int t    = threadIdx.x;
  const int wave = t >> 6;
  const int lane = t & 63;
  const int m    = lane & 15;
  const int quad = lane >> 4;
  const int bid  = blockIdx.x;
  const bool isC = bid >= (N_LITS / 64);
  const int r0   = (isC ? bid - N_LITS / 64 : bid) * 64;
  const float* A = isC ? c_embs : l_embs;
  const int koff = isC ? FEAT : 0;   // which half of W1T's K range
  const int wn   = wave * 64;

  const int sr  = t >> 2;
  const int sub = t & 3;
  const float* pA = A + (size_t)(r0 + sr) * FEAT + sub * 4;
  bf16_t* sdst = Abuf + sr * ASTR + sub * 4;

  f32x4 acc[4][4];
#pragma unroll
  for (int mt = 0; mt < 4; ++mt)
#pragma unroll
    for (int nt = 0; nt < 4; ++nt) acc[mt][nt] = (f32x4){0.f, 0.f, 0.f, 0.f};

  const bf16_t* wb1 = W1T + (size_t)(wn + m) * F2 + koff + quad * 8;

  // prologue: stage chunk 0
  {
    float4 v[6];
#pragma unroll
    for (int q = 0; q < 6; ++q) v[q] = *(const float4*)(pA + q * 16);
#pragma unroll
    for (int q = 0; q < 6; ++q) {
      bf16x4 c;
      c[0] = (bf16_t)v[q].x; c[1] = (bf16_t)v[q].y;
      c[2] = (bf16_t)v[q].z; c[3] = (bf16_t)v[q].w;
      *(bf16x4*)(sdst + q * 16) = c;
    }
  }

  for (int cc = 0; cc < 4; ++cc) {
    float4 vn[6];
    if (cc < 3) {
#pragma unroll
      for (int q = 0; q < 6; ++q) vn[q] = *(const float4*)(pA + (cc + 1) * 96 + q * 16);
    }
    __syncthreads();
#pragma unroll
    for (int s = 0; s < 3; ++s) {
      bf16x8 af[4];
#pragma unroll
      for (int mt = 0; mt < 4; ++mt)
        af[mt] = *(const bf16x8*)(Abuf + (mt * 16 + m) * ASTR + s * 32 + quad * 8);
      const bf16_t* wb = wb1 + cc * 96 + s * 32;
#pragma unroll
      for (int nt = 0; nt < 4; ++nt) {
        bf16x8 b = *(const bf16x8*)(wb + (size_t)nt * 16 * F2);
#pragma unroll
        for (int mt = 0; mt < 4; ++mt)
          acc[mt][nt] = __builtin_amdgcn_mfma_f32_16x16x32_bf16(af[mt], b, acc[mt][nt], 0, 0, 0);
      }
    }
    if (cc < 3) {
      __syncthreads();
#pragma unroll
      for (int q = 0; q < 6; ++q) {
        bf16x4 c;
        c[0] = (bf16_t)vn[q].x; c[1] = (bf16_t)vn[q].y;
        c[2] = (bf16_t)vn[q].z; c[3] = (bf16_t)vn[q].w;
        *(bf16x4*)(sdst + q * 16) = c;
      }
    }
  }

  // ---- epilogue: fragments -> LDS (b1 folded into XC; no relu here) ----
  __syncthreads();   // all Abuf reads done before overwrite
#pragma unroll
  for (int nt = 0; nt < 4; ++nt) {
    int col = wn + nt * 16 + m;
    float badd = isC ? b1[col] : 0.0f;
#pragma unroll
    for (int mt = 0; mt < 4; ++mt)
#pragma unroll
      for (int r = 0; r < 4; ++r)
        smem2[(mt * 16 + quad * 4 + r) * XSTR + col] = (bf16_t)(acc[mt][nt][r] + badd);
  }
  __syncthreads();

  // coalesced store: 64 rows x 32 16B-chunks = 2048 chunks; 256 threads x 8
  bf16_t* X = isC ? XCb : XLb;
#pragma unroll
  for (int k = 0; k < 8; ++k) {
    int c    = t + k * 256;
    int row  = c >> 5;           // 32 chunks per row -> row in [0,64)
    int coff = (c & 31) * 8;
    bf16x8 v = *(const bf16x8*)(smem2 + row * XSTR + coff);
    *(bf16x8*)(X + (size_t)(r0 + row) * H1 + coff) = v;
  }
}

// ---- per-edge: h1 = relu(XL[i] + XC[j]) in-register, layers 2-4, atomics ----
// Processes the j-bucketed pairs list; XCD-chunked swizzle -> each XCD's L2 holds
// its contiguous j-range of XC. 64 edges/block, 4 waves x 16 edges, no barriers.
__global__ __launch_bounds__(256, 8) void k_edge2(
    const bf16_t* __restrict__ XLb, const bf16_t* __restrict__ XCb,
    const int2* __restrict__ pairs,
    const bf16_t* __restrict__ W2T, const bf16_t* __restrict__ W3T,
    const float* __restrict__ b2, const float* __restrict__ b3,
    const float* __restrict__ W4, const float* __restrict__ b4,
    float* __restrict__ sc)
{
  __shared__ __align__(16) bf16_t h2s[64 * H2STR];

  const int t    = threadIdx.x;
  const int wave = t >> 6;
  const int lane = t & 63;
  const int m    = lane & 15;
  const int quad = lane >> 4;
  // bijective XCD-chunked swizzle (grid 8192 % 8 == 0)
  const int bid  = blockIdx.x;
  const int swz  = (bid & 7) * (int)(gridDim.x >> 3) + (bid >> 3);
  const int e0   = swz * 64;
  const int er   = wave * 16;

  const int2 ij = pairs[e0 + er + m];
  const int ri = ij.x;
  const int rj = ij.y;
  const size_t baseL = (size_t)ri * H1;
  const size_t baseC = (size_t)rj * H1;

  f32x4 acc2[4];
#pragma unroll
  for (int nt = 0; nt < 4; ++nt) acc2[nt] = (f32x4){0.f, 0.f, 0.f, 0.f};

  // layer 2: K=256 in 8 steps of 32; A built in-register from gathered rows
#pragma unroll
  for (int g = 0; g < 2; ++g) {
    bf16x8 xa[4], ya[4];
#pragma unroll
    for (int u = 0; u < 4; ++u) {
      const int off = (g * 4 + u) * 32 + quad * 8;
      xa[u] = *(const bf16x8*)(XLb + baseL + off);
      ya[u] = *(const bf16x8*)(XCb + baseC + off);
    }
    bf16x8 a2[4];
#pragma unroll
    for (int u = 0; u < 4; ++u) {
#pragma unroll
      for (int jj = 0; jj < 8; ++jj)
        a2[u][jj] = (bf16_t)fmaxf((float)xa[u][jj] + (float)ya[u][jj], 0.f);
    }
#pragma unroll
    for (int u = 0; u < 4; ++u) {
      const int s2 = g * 4 + u;
#pragma unroll
      for (int nt = 0; nt < 4; ++nt) {
        bf16x8 b = *(const bf16x8*)(W2T + (size_t)(nt * 16 + m) * H1 + s2 * 32 + quad * 8);
        acc2[nt] = __builtin_amdgcn_mfma_f32_16x16x32_bf16(a2[u], b, acc2[nt], 0, 0, 0);
      }
    }
  }

  // h2 -> LDS (rows er..er+15 owned by this wave; no barrier needed)
#pragma unroll
  for (int nt = 0; nt < 4; ++nt) {
    float bb = b2[nt * 16 + m];
#pragma unroll
    for (int r = 0; r < 4; ++r)
      h2s[(er + quad * 4 + r) * H2STR + nt * 16 + m] =
          (bf16_t)fmaxf(acc2[nt][r] + bb, 0.0f);
  }

  // layer 3: C3[16,32] = h2[16,64] @ W3pad
  f32x4 acc3[2];
#pragma unroll
  for (int nt = 0; nt < 2; ++nt) acc3[nt] = (f32x4){0.f, 0.f, 0.f, 0.f};
#pragma unroll
  for (int s3 = 0; s3 < 2; ++s3) {
    bf16x8 a3 = *(const bf16x8*)(h2s + (er + m) * H2STR + s3 * 32 + quad * 8);
#pragma unroll
    for (int nt = 0; nt < 2; ++nt) {
      bf16x8 b = *(const bf16x8*)(W3T + (size_t)(nt * 16 + m) * H2 + s3 * 32 + quad * 8);
      acc3[nt] = __builtin_amdgcn_mfma_f32_16x16x32_bf16(a3, b, acc3[nt], 0, 0, 0);
    }
  }

  // layer 4 + per-clause atomics (interleaved {sum,count})
  float b3A = b3[m];
  float b3B = (m + 16 < 20) ? b3[m + 16] : 0.0f;
  float w4A = W4[m];
  float w4B = (m + 16 < 20) ? W4[m + 16] : 0.0f;

  float p[4];
#pragma unroll
  for (int r = 0; r < 4; ++r) {
    float hA = fmaxf(acc3[0][r] + b3A, 0.0f);
    float hB = fmaxf(acc3[1][r] + b3B, 0.0f);
    p[r] = hA * w4A + hB * w4B;
  }
#pragma unroll
  for (int d = 1; d < 16; d <<= 1) {
#pragma unroll
    for (int r = 0; r < 4; ++r) p[r] += __shfl_xor(p[r], d, 64);
  }

  // shfl must run with ALL lanes active (inactive-source shfl is undefined):
  // row er+quad*4+r's j lives in lane quad*4+r (that lane's m == quad*4+r).
  int ejr[4];
#pragma unroll
  for (int r = 0; r < 4; ++r) ejr[r] = __shfl(rj, quad * 4 + r, 64);

  if (m == 0) {
    float bb4 = b4[0];
#pragma unroll
    for (int r = 0; r < 4; ++r) {
      atomicAdd(&sc[2 * ejr[r]], p[r] + bb4);
      atomicAdd(&sc[2 * ejr[r] + 1], 1.0f);
    }
  }
}

// out[e] = sc[ej].sum / max(sc[ej].count, 1) — one 8B gather per edge
__global__ void k_gather(const float2* __restrict__ sc,
                         const int* __restrict__ edge_j, float* __restrict__ out) {
  int e = blockIdx.x * blockDim.x + threadIdx.x;
  if (e >= N_EDGES) return;
  float2 v = sc[edge_j[e]];
  out[e] = v.x / fmaxf(v.y, 1.0f);
}

extern "C" void kernel_launch(void* const* d_in, const int* in_sizes, int n_in,
                              void* d_out, int out_size, void* d_ws, size_t ws_size,
                              hipStream_t stream) {
  const float* l_embs = (const float*)d_in[0];
  const float* c_embs = (const float*)d_in[1];
  const int*   edge_i = (const int*)d_in[2];
  const int*   edge_j = (const int*)d_in[3];
  const float* W1 = (const float*)d_in[4];
  const float* b1 = (const float*)d_in[5];
  const float* W2 = (const float*)d_in[6];
  const float* b2 = (const float*)d_in[7];
  const float* W3 = (const float*)d_in[8];
  const float* b3 = (const float*)d_in[9];
  const float* W4 = (const float*)d_in[10];
  const float* b4 = (const float*)d_in[11];
  float* out = (float*)d_out;

  char* ws = (char*)d_ws;
  bf16_t* W1T  = (bf16_t*)(ws + OFF_W1T);
  bf16_t* W2T  = (bf16_t*)(ws + OFF_W2T);
  bf16_t* W3T  = (bf16_t*)(ws + OFF_W3T);
  float*  sc   = (float*)(ws + OFF_SC);
  int*    hist = (int*)(ws + OFF_HIST);
  int*    curs = (int*)(ws + OFF_CURS);
  int2*   pairs= (int2*)(ws + OFF_PAIRS);
  bf16_t* XLb  = (bf16_t*)(ws + OFF_X);
  bf16_t* XCb  = (bf16_t*)(ws + OFF_X + XL_BYTES);

  // weights transpose + sc/hist zeroing (976 blocks x 256 = 249856 threads)
  k_prep<<<976, 256, 0, stream>>>(W1, W2, W3, W1T, W2T, W3T,
                                  (float4*)sc, (int4*)hist);

  // j-bucketing of edges (order-invariant)
  k_bin_count<<<N_EDGES / 256, 256, 0, stream>>>(edge_j, hist);
  k_scan<<<1, 256, 0, stream>>>(hist, curs);
  k_scatter<<<N_EDGES / 256, 256, 0, stream>>>(edge_i, edge_j, curs, pairs);

  const int pre_grid = N_LITS / 64 + N_CLAUSES / 64;  // 3072
  k_pre<<<pre_grid, 256, 0, stream>>>(l_embs, c_embs, W1T, b1, XLb, XCb);

  k_edge2<<<N_EDGES / 64, 256, 0, stream>>>(
      XLb, XCb, pairs, W2T, W3T, b2, b3, W4, b4, sc);

  k_gather<<<N_EDGES / 256, 256, 0, stream>>>((const float2*)sc, edge_j, out);
}

// Round 10
// 543.405 us; speedup vs baseline: 1.3805x; 1.2462x over previous
//
#include <hip/hip_runtime.h>
#include <hip/hip_bf16.h>

#define N_LITS    131072
#define N_CLAUSES 65536
#define N_EDGES   524288
#define FEAT      384
#define F2        768
#define H1        256
#define H2        64

typedef __bf16 bf16_t;
typedef __attribute__((ext_vector_type(8))) __bf16 bf16x8;
typedef __attribute__((ext_vector_type(4))) __bf16 bf16x4;
typedef __attribute__((ext_vector_type(4))) float f32x4;

// ---- workspace layout (bytes) ----
#define OFF_W1T   0                               // bf16 [256][768]
#define OFF_W2T   (OFF_W1T + 256 * 768 * 2)       // bf16 [64][256]
#define OFF_W3T   (OFF_W2T + 64 * 256 * 2)        // bf16 [32][64]
#define OFF_SC    (OFF_W3T + 32 * 64 * 2)         // f32 [65536][2] {sum,count}
#define OFF_X     (OFF_SC + 65536 * 8)            // XL bf16[131072][256], XC bf16[65536][256]
#define XL_BYTES  ((size_t)N_LITS * H1 * 2)
#define XC_BYTES  ((size_t)N_CLAUSES * H1 * 2)

// LDS strides (elements)
#define ASTR  104  // k_pre staging row stride: 96 + 8 pad
#define XSTR  264  // k_pre epilogue row stride: 256 + 8 pad
#define W2STR 264  // W2 LDS row stride: 256 + 8 pad (uniform 8/bank on b128 reads)
#define H2STR 72   // h2 row stride: 64 + 8 pad

// Fused: transpose+cast W1,W2,W3; zero sc. Grid 968*256 = 247808 threads exactly.
__global__ void k_prep(const float* __restrict__ W1, const float* __restrict__ W2,
                       const float* __restrict__ W3, bf16_t* __restrict__ W1T,
                       bf16_t* __restrict__ W2T, bf16_t* __restrict__ W3T,
                       float4* __restrict__ scz) {
  int idx = blockIdx.x * blockDim.x + threadIdx.x;
  if (idx < 196608) {
    int n = idx / 768, k = idx - n * 768;
    W1T[idx] = (bf16_t)W1[k * 256 + n];
  } else if (idx < 196608 + 16384) {
    int i = idx - 196608;
    int n = i / 256, k = i - n * 256;
    W2T[i] = (bf16_t)W2[k * 64 + n];
  } else if (idx < 196608 + 16384 + 2048) {
    int i = idx - 196608 - 16384;
    int n = i / 64, k = i - n * 64;
    W3T[i] = (bf16_t)((n < 20) ? W3[k * 20 + n] : 0.0f);
  } else if (idx >= 215040) {
    scz[idx - 215040] = (float4){0.f, 0.f, 0.f, 0.f};  // 32768 float4 = sc
  }
}

// ---- precompute: XL = l_embs @ W1_top ; XC = c_embs @ W1_bot + b1 (bf16 out) ----
// Staged cooperative LDS pipeline (known-good round-5 structure, 4 blocks/CU).
__global__ __launch_bounds__(256, 4) void k_pre(
    const float* __restrict__ l_embs, const float* __restrict__ c_embs,
    const bf16_t* __restrict__ W1T, const float* __restrict__ b1,
    bf16_t* __restrict__ XLb, bf16_t* __restrict__ XCb)
{
  __shared__ __align__(16) bf16_t smem2[64 * XSTR];  // staging (ASTR view) U epilogue
  bf16_t* Abuf = smem2;

  const int t    = threadIdx.x;
  const int wave = t >> 6;
  const int lane = t & 63;
  const int m    = lane & 15;
  const int quad = lane >> 4;
  const int bid  = blockIdx.x;
  const bool isC = bid >= (N_LITS / 64);
  const int r0   = (isC ? bid - N_LITS / 64 : bid) * 64;
  const float* A = isC ? c_embs : l_embs;
  const int koff = isC ? FEAT : 0;
  const int wn   = wave * 64;

  const int sr  = t >> 2;
  const int sub = t & 3;
  const float* pA = A + (size_t)(r0 + sr) * FEAT + sub * 4;
  bf16_t* sdst = Abuf + sr * ASTR + sub * 4;

  f32x4 acc[4][4];
#pragma unroll
  for (int mt = 0; mt < 4; ++mt)
#pragma unroll
    for (int nt = 0; nt < 4; ++nt) acc[mt][nt] = (f32x4){0.f, 0.f, 0.f, 0.f};

  const bf16_t* wb1 = W1T + (size_t)(wn + m) * F2 + koff + quad * 8;

  // prologue: stage chunk 0
  {
    float4 v[6];
#pragma unroll
    for (int q = 0; q < 6; ++q) v[q] = *(const float4*)(pA + q * 16);
#pragma unroll
    for (int q = 0; q < 6; ++q) {
      bf16x4 c;
      c[0] = (bf16_t)v[q].x; c[1] = (bf16_t)v[q].y;
      c[2] = (bf16_t)v[q].z; c[3] = (bf16_t)v[q].w;
      *(bf16x4*)(sdst + q * 16) = c;
    }
  }

  for (int cc = 0; cc < 4; ++cc) {
    float4 vn[6];
    if (cc < 3) {
#pragma unroll
      for (int q = 0; q < 6; ++q) vn[q] = *(const float4*)(pA + (cc + 1) * 96 + q * 16);
    }
    __syncthreads();
#pragma unroll
    for (int s = 0; s < 3; ++s) {
      bf16x8 af[4];
#pragma unroll
      for (int mt = 0; mt < 4; ++mt)
        af[mt] = *(const bf16x8*)(Abuf + (mt * 16 + m) * ASTR + s * 32 + quad * 8);
      const bf16_t* wb = wb1 + cc * 96 + s * 32;
#pragma unroll
      for (int nt = 0; nt < 4; ++nt) {
        bf16x8 b = *(const bf16x8*)(wb + (size_t)nt * 16 * F2);
#pragma unroll
        for (int mt = 0; mt < 4; ++mt)
          acc[mt][nt] = __builtin_amdgcn_mfma_f32_16x16x32_bf16(af[mt], b, acc[mt][nt], 0, 0, 0);
      }
    }
    if (cc < 3) {
      __syncthreads();
#pragma unroll
      for (int q = 0; q < 6; ++q) {
        bf16x4 c;
        c[0] = (bf16_t)vn[q].x; c[1] = (bf16_t)vn[q].y;
        c[2] = (bf16_t)vn[q].z; c[3] = (bf16_t)vn[q].w;
        *(bf16x4*)(sdst + q * 16) = c;
      }
    }
  }

  // epilogue: fragments -> LDS transpose (b1 folded into XC)
  __syncthreads();
#pragma unroll
  for (int nt = 0; nt < 4; ++nt) {
    int col = wn + nt * 16 + m;
    float badd = isC ? b1[col] : 0.0f;
#pragma unroll
    for (int mt = 0; mt < 4; ++mt)
#pragma unroll
      for (int r = 0; r < 4; ++r)
        smem2[(mt * 16 + quad * 4 + r) * XSTR + col] = (bf16_t)(acc[mt][nt][r] + badd);
  }
  __syncthreads();

  // coalesced store: 2048 16B-chunks; 256 threads x 8
  bf16_t* X = isC ? XCb : XLb;
#pragma unroll
  for (int k = 0; k < 8; ++k) {
    int c    = t + k * 256;
    int row  = c >> 5;
    int coff = (c & 31) * 8;
    bf16x8 v = *(const bf16x8*)(smem2 + row * XSTR + coff);
    *(bf16x8*)(X + (size_t)(r0 + row) * H1 + coff) = v;
  }
}

// ---- per-edge MLP: 128 edges/block, 8 waves x 16 edges; W2 staged in LDS ----
// Cuts per-wave VMEM instruction count ~45%: B-fragments come from the LDS pipe.
__global__ __launch_bounds__(512, 6) void k_edge2(
    const bf16_t* __restrict__ XLb, const bf16_t* __restrict__ XCb,
    const int* __restrict__ edge_i, const int* __restrict__ edge_j,
    const bf16_t* __restrict__ W2T, const bf16_t* __restrict__ W3T,
    const float* __restrict__ b2, const float* __restrict__ b3,
    const float* __restrict__ W4, const float* __restrict__ b4,
    float* __restrict__ sc)
{
  __shared__ __align__(16) bf16_t W2s[64 * W2STR];   // 33792 B
  __shared__ __align__(16) bf16_t h2s[128 * H2STR];  // 18432 B

  const int t = threadIdx.x;

  // stage W2T [64][256] -> W2s [64][W2STR]: 2048 chunks of 16B; 512 thr x 4
#pragma unroll
  for (int k = 0; k < 4; ++k) {
    int c   = t + k * 512;
    int row = c >> 5;
    int col = (c & 31) * 8;
    *(bf16x8*)(&W2s[row * W2STR + col]) = *(const bf16x8*)(W2T + row * 256 + col);
  }
  __syncthreads();

  const int wave = t >> 6;        // 0..7
  const int lane = t & 63;
  const int m    = lane & 15;
  const int quad = lane >> 4;
  const int e0   = blockIdx.x * 128;
  const int er   = wave * 16;

  const int e  = e0 + er + m;
  const int ri = edge_i[e];
  const int rj = edge_j[e];
  const size_t baseL = (size_t)ri * H1;
  const size_t baseC = (size_t)rj * H1;

  f32x4 acc2[4];
#pragma unroll
  for (int nt = 0; nt < 4; ++nt) acc2[nt] = (f32x4){0.f, 0.f, 0.f, 0.f};

  // layer 2: K=256 in 8 steps of 32; A from gathered X rows, B from LDS
#pragma unroll
  for (int g = 0; g < 2; ++g) {
    bf16x8 xa[4], ya[4];
#pragma unroll
    for (int u = 0; u < 4; ++u) {
      const int off = (g * 4 + u) * 32 + quad * 8;
      xa[u] = *(const bf16x8*)(XLb + baseL + off);
      ya[u] = *(const bf16x8*)(XCb + baseC + off);
    }
    bf16x8 a2[4];
#pragma unroll
    for (int u = 0; u < 4; ++u) {
#pragma unroll
      for (int jj = 0; jj < 8; ++jj)
        a2[u][jj] = (bf16_t)fmaxf((float)xa[u][jj] + (float)ya[u][jj], 0.f);
    }
#pragma unroll
    for (int u = 0; u < 4; ++u) {
      const int s2 = g * 4 + u;
#pragma unroll
      for (int nt = 0; nt < 4; ++nt) {
        bf16x8 b = *(const bf16x8*)(&W2s[(nt * 16 + m) * W2STR + s2 * 32 + quad * 8]);
        acc2[nt] = __builtin_amdgcn_mfma_f32_16x16x32_bf16(a2[u], b, acc2[nt], 0, 0, 0);
      }
    }
  }

  // h2 -> LDS (rows er..er+15 owned by this wave; no barrier needed)
#pragma unroll
  for (int nt = 0; nt < 4; ++nt) {
    float bb = b2[nt * 16 + m];
#pragma unroll
    for (int r = 0; r < 4; ++r)
      h2s[(er + quad * 4 + r) * H2STR + nt * 16 + m] =
          (bf16_t)fmaxf(acc2[nt][r] + bb, 0.0f);
  }

  // layer 3: C3[16,32] = h2[16,64] @ W3pad (W3T tiny -> L1-hot global)
  f32x4 acc3[2];
#pragma unroll
  for (int nt = 0; nt < 2; ++nt) acc3[nt] = (f32x4){0.f, 0.f, 0.f, 0.f};
#pragma unroll
  for (int s3 = 0; s3 < 2; ++s3) {
    bf16x8 a3 = *(const bf16x8*)(h2s + (er + m) * H2STR + s3 * 32 + quad * 8);
#pragma unroll
    for (int nt = 0; nt < 2; ++nt) {
      bf16x8 b = *(const bf16x8*)(W3T + (size_t)(nt * 16 + m) * H2 + s3 * 32 + quad * 8);
      acc3[nt] = __builtin_amdgcn_mfma_f32_16x16x32_bf16(a3, b, acc3[nt], 0, 0, 0);
    }
  }

  // layer 4 + per-clause atomics (interleaved {sum,count})
  float b3A = b3[m];
  float b3B = (m + 16 < 20) ? b3[m + 16] : 0.0f;
  float w4A = W4[m];
  float w4B = (m + 16 < 20) ? W4[m + 16] : 0.0f;

  float p[4];
#pragma unroll
  for (int r = 0; r < 4; ++r) {
    float hA = fmaxf(acc3[0][r] + b3A, 0.0f);
    float hB = fmaxf(acc3[1][r] + b3B, 0.0f);
    p[r] = hA * w4A + hB * w4B;
  }
#pragma unroll
  for (int d = 1; d < 16; d <<= 1) {
#pragma unroll
    for (int r = 0; r < 4; ++r) p[r] += __shfl_xor(p[r], d, 64);
  }

  if (m == 0) {
    float bb4 = b4[0];
#pragma unroll
    for (int r = 0; r < 4; ++r) {
      int row = er + quad * 4 + r;
      int ej = edge_j[e0 + row];
      atomicAdd(&sc[2 * ej], p[r] + bb4);
      atomicAdd(&sc[2 * ej + 1], 1.0f);
    }
  }
}

// out[e] = sc[ej].sum / max(sc[ej].count, 1) — one 8B gather per edge
__global__ void k_gather(const float2* __restrict__ sc,
                         const int* __restrict__ edge_j, float* __restrict__ out) {
  int e = blockIdx.x * blockDim.x + threadIdx.x;
  if (e >= N_EDGES) return;
  float2 v = sc[edge_j[e]];
  out[e] = v.x / fmaxf(v.y, 1.0f);
}

extern "C" void kernel_launch(void* const* d_in, const int* in_sizes, int n_in,
                              void* d_out, int out_size, void* d_ws, size_t ws_size,
                              hipStream_t stream) {
  const float* l_embs = (const float*)d_in[0];
  const float* c_embs = (const float*)d_in[1];
  const int*   edge_i = (const int*)d_in[2];
  const int*   edge_j = (const int*)d_in[3];
  const float* W1 = (const float*)d_in[4];
  const float* b1 = (const float*)d_in[5];
  const float* W2 = (const float*)d_in[6];
  const float* b2 = (const float*)d_in[7];
  const float* W3 = (const float*)d_in[8];
  const float* b3 = (const float*)d_in[9];
  const float* W4 = (const float*)d_in[10];
  const float* b4 = (const float*)d_in[11];
  float* out = (float*)d_out;

  char* ws = (char*)d_ws;
  bf16_t* W1T = (bf16_t*)(ws + OFF_W1T);
  bf16_t* W2T = (bf16_t*)(ws + OFF_W2T);
  bf16_t* W3T = (bf16_t*)(ws + OFF_W3T);
  float*  sc  = (float*)(ws + OFF_SC);
  bf16_t* XLb = (bf16_t*)(ws + OFF_X);
  bf16_t* XCb = (bf16_t*)(ws + OFF_X + XL_BYTES);

  // weights transpose + sc zeroing (968 blocks x 256 = 247808 threads exactly)
  k_prep<<<968, 256, 0, stream>>>(W1, W2, W3, W1T, W2T, W3T, (float4*)sc);

  const int pre_grid = N_LITS / 64 + N_CLAUSES / 64;  // 3072
  k_pre<<<pre_grid, 256, 0, stream>>>(l_embs, c_embs, W1T, b1, XLb, XCb);

  k_edge2<<<N_EDGES / 128, 512, 0, stream>>>(
      XLb, XCb, edge_i, edge_j, W2T, W3T, b2, b3, W4, b4, sc);

  k_gather<<<N_EDGES / 256, 256, 0, stream>>>((const float2*)sc, edge_j, out);
}